// Round 3
// baseline (980.557 us; speedup 1.0000x reference)
//
#include <hip/hip_runtime.h>

// B=8, N=256, H=256
// out[b,i,h] = Ux[b,i,h] + (sum_j eg[b,i,j,h]*Vx[b,j,h]) / (1e-20 + sum_j eg[b,i,j,h])
//
// v4: SINGLE fused kernel, ZERO workspace use. Theory: the ~550 us residual in
// dur_us is the harness's 2 GiB d_ws poison fills on the timed stream (four
// structurally different fuse_gate variants all landed 668-684 us; the fills
// are the only invariant). Each block recomputes its Vx quarter-panel into LDS
// (redundancy: 16 i-tiles share it -> 2.2 GMAC total ~= 27 us chip-wide VALU,
// overlapped with the co-resident block's eg streaming), streams its eg slice
// exactly once, and recomputes its Ux slice in the epilogue. No d_ws, no Vx
// HBM round-trip, no out RMW, no second launch, no nontemporal flag.
//
// Grid: (hq=4, it=16, b=8) = 512 blocks x 512 threads. LDS 64 KB -> 2 blk/CU.

typedef float f4 __attribute__((ext_vector_type(4)));

#define NF4 64   // f4 per 256-float row

__device__ __forceinline__ f4 shfl_xor_f4(f4 v, int m) {
  f4 r;
  r.x = __shfl_xor(v.x, m, 64);
  r.y = __shfl_xor(v.y, m, 64);
  r.z = __shfl_xor(v.z, m, 64);
  r.w = __shfl_xor(v.w, m, 64);
  return r;
}

__global__ __launch_bounds__(512, 4) void node_fused(
    const float* __restrict__ x, const float* __restrict__ eg,
    const float* __restrict__ U_w, const float* __restrict__ U_b,
    const float* __restrict__ V_w, const float* __restrict__ V_b,
    float* __restrict__ out) {
  __shared__ float Vxs[256][64];   // 64 KB: Vx[j][h-quarter-local]

  const int t  = threadIdx.x;
  const int hq = blockIdx.x;   // 0..3   h-quarter (64 h)
  const int it = blockIdx.y;   // 0..15  i-tile (16 i)
  const int b  = blockIdx.z;   // 0..7

  const f4* x4  = (const f4*)x;
  const f4* Vw4 = (const f4*)V_w;
  const f4* Uw4 = (const f4*)U_w;

  // ---- Phase 1: Vx quarter-panel (256 j x 64 h) -> LDS ----
  // thread tile: 4 j x 8 h. jq = t>>3 (0..63), hg = t&7 (0..7).
  {
    const int jq = t >> 3;
    const int hg = t & 7;
    const int j0 = jq * 4;
    const int hrow = hq * 64 + hg * 8;          // global V_w row base

    float acc[4][8] = {};
    const f4* xb = x4 + (size_t)(b * 256 + j0) * NF4;
    const f4* vb = Vw4 + (size_t)hrow * NF4;
    for (int k4 = 0; k4 < 64; ++k4) {
      f4 xa0 = xb[0 * NF4 + k4];
      f4 xa1 = xb[1 * NF4 + k4];
      f4 xa2 = xb[2 * NF4 + k4];
      f4 xa3 = xb[3 * NF4 + k4];
      #pragma unroll
      for (int c = 0; c < 8; ++c) {
        f4 w = vb[c * NF4 + k4];
        acc[0][c] += xa0.x * w.x + xa0.y * w.y + xa0.z * w.z + xa0.w * w.w;
        acc[1][c] += xa1.x * w.x + xa1.y * w.y + xa1.z * w.z + xa1.w * w.w;
        acc[2][c] += xa2.x * w.x + xa2.y * w.y + xa2.z * w.z + xa2.w * w.w;
        acc[3][c] += xa3.x * w.x + xa3.y * w.y + xa3.z * w.z + xa3.w * w.w;
      }
    }
    const f4* Vb4 = (const f4*)V_b;
    const f4 bia = Vb4[(hrow >> 2) + 0];
    const f4 bib = Vb4[(hrow >> 2) + 1];
    #pragma unroll
    for (int r = 0; r < 4; ++r) {
      f4 lo = {acc[r][0] + bia.x, acc[r][1] + bia.y,
               acc[r][2] + bia.z, acc[r][3] + bia.w};
      f4 hi = {acc[r][4] + bib.x, acc[r][5] + bib.y,
               acc[r][6] + bib.z, acc[r][7] + bib.w};
      *(f4*)&Vxs[j0 + r][hg * 8 + 0] = lo;
      *(f4*)&Vxs[j0 + r][hg * 8 + 4] = hi;
    }
  }
  __syncthreads();

  // ---- Phase 2+3: stream eg, accumulate num/den; epilogue recomputes Ux ----
  const int lane = t & 63;
  const int w    = t >> 6;       // wave 0..7
  const int jsub = lane >> 4;    // 0..3: owns j in [jsub*64, jsub*64+64)
  const int h4   = lane & 15;    // f4 index within the h-quarter

  const f4* Ub4 = (const f4*)U_b;
  const f4 ubias = Ub4[hq * 16 + h4];

  #pragma unroll
  for (int ii = 0; ii < 2; ++ii) {
    const int i = it * 16 + w * 2 + ii;
    const f4* egp = (const f4*)eg +
        (size_t)(b * 256 + i) * 256 * NF4 + (size_t)(hq * 16 + h4);
    const int jb = jsub * 64;

    f4 n0 = {0.f, 0.f, 0.f, 0.f}, n1 = {0.f, 0.f, 0.f, 0.f};
    f4 d0 = {0.f, 0.f, 0.f, 0.f}, d1 = {0.f, 0.f, 0.f, 0.f};

    #pragma unroll 1
    for (int jj = 0; jj < 64; jj += 8) {
      const f4* ep = egp + (size_t)(jb + jj) * NF4;   // per-j stride 1024 B
      f4 e0 = ep[0 * NF4];
      f4 e1 = ep[1 * NF4];
      f4 e2 = ep[2 * NF4];
      f4 e3 = ep[3 * NF4];
      f4 e4 = ep[4 * NF4];
      f4 e5 = ep[5 * NF4];
      f4 e6 = ep[6 * NF4];
      f4 e7 = ep[7 * NF4];
      f4 v0 = *(const f4*)&Vxs[jb + jj + 0][h4 * 4];
      f4 v1 = *(const f4*)&Vxs[jb + jj + 1][h4 * 4];
      f4 v2 = *(const f4*)&Vxs[jb + jj + 2][h4 * 4];
      f4 v3 = *(const f4*)&Vxs[jb + jj + 3][h4 * 4];
      f4 v4 = *(const f4*)&Vxs[jb + jj + 4][h4 * 4];
      f4 v5 = *(const f4*)&Vxs[jb + jj + 5][h4 * 4];
      f4 v6 = *(const f4*)&Vxs[jb + jj + 6][h4 * 4];
      f4 v7 = *(const f4*)&Vxs[jb + jj + 7][h4 * 4];
      n0 += e0 * v0;  d0 += e0;
      n1 += e1 * v1;  d1 += e1;
      n0 += e2 * v2;  d0 += e2;
      n1 += e3 * v3;  d1 += e3;
      n0 += e4 * v4;  d0 += e4;
      n1 += e5 * v5;  d1 += e5;
      n0 += e6 * v6;  d0 += e6;
      n1 += e7 * v7;  d1 += e7;
    }
    f4 num = n0 + n1;
    f4 den = d0 + d1;
    // combine the 4 jsub groups: lanes ^16 and ^32 hold the other j-subsets
    num += shfl_xor_f4(num, 16);
    den += shfl_xor_f4(den, 16);
    num += shfl_xor_f4(num, 32);
    den += shfl_xor_f4(den, 32);

    // Ux for (i, h = hq*64 + h4*4 + 0..3); k split 4-way by jsub
    f4 ux = {0.f, 0.f, 0.f, 0.f};
    {
      const f4* xi = x4 + (size_t)(b * 256 + i) * NF4 + jsub * 16;
      const f4* u0 = Uw4 + (size_t)(hq * 64 + h4 * 4 + 0) * NF4 + jsub * 16;
      const f4* u1 = Uw4 + (size_t)(hq * 64 + h4 * 4 + 1) * NF4 + jsub * 16;
      const f4* u2 = Uw4 + (size_t)(hq * 64 + h4 * 4 + 2) * NF4 + jsub * 16;
      const f4* u3 = Uw4 + (size_t)(hq * 64 + h4 * 4 + 3) * NF4 + jsub * 16;
      #pragma unroll 4
      for (int k4 = 0; k4 < 16; ++k4) {
        f4 xv = xi[k4];
        f4 w0 = u0[k4];
        f4 w1 = u1[k4];
        f4 w2 = u2[k4];
        f4 w3 = u3[k4];
        ux.x += xv.x * w0.x + xv.y * w0.y + xv.z * w0.z + xv.w * w0.w;
        ux.y += xv.x * w1.x + xv.y * w1.y + xv.z * w1.z + xv.w * w1.w;
        ux.z += xv.x * w2.x + xv.y * w2.y + xv.z * w2.z + xv.w * w2.w;
        ux.w += xv.x * w3.x + xv.y * w3.y + xv.z * w3.z + xv.w * w3.w;
      }
    }
    ux += shfl_xor_f4(ux, 16);
    ux += shfl_xor_f4(ux, 32);

    if (jsub == 0) {
      f4 eps = {1e-20f, 1e-20f, 1e-20f, 1e-20f};
      f4 o = ux + ubias + num / (eps + den);
      ((f4*)out)[(size_t)(b * 256 + i) * NF4 + hq * 16 + h4] = o;
    }
  }
}

extern "C" void kernel_launch(void* const* d_in, const int* in_sizes, int n_in,
                              void* d_out, int out_size, void* d_ws, size_t ws_size,
                              hipStream_t stream) {
  const float* x   = (const float*)d_in[0];
  const float* eg  = (const float*)d_in[1];
  const float* U_w = (const float*)d_in[2];
  const float* U_b = (const float*)d_in[3];
  const float* V_w = (const float*)d_in[4];
  const float* V_b = (const float*)d_in[5];
  float* out = (float*)d_out;
  (void)d_ws; (void)ws_size;  // workspace intentionally untouched

  node_fused<<<dim3(4, 16, 8), 512, 0, stream>>>(x, eg, U_w, U_b, V_w, V_b, out);
}

// Round 4
// 688.796 us; speedup vs baseline: 1.4236x; 1.4236x over previous
//
#include <hip/hip_runtime.h>

// B=8, N=256, H=256
// out[b,i,h] = Ux[b,i,h] + (sum_j eg[b,i,j,h]*Vx[b,j,h]) / (1e-20 + sum_j eg[b,i,j,h])
// Structure: gemm_uv (Ux->out, Vx->ws) ; fuse_partial (eg stream -> 16MB partials in ws)
//            ; combine (partials + Ux -> out).
// fuse_partial maximizes parallelism on every axis: 32768 waves (4 occupancy
// rounds), 16 contiguous 1KB loads per wave in two 8-deep batches, NT on eg.

typedef float f4 __attribute__((ext_vector_type(4)));
typedef float f2 __attribute__((ext_vector_type(2)));

#define S36 36  // 32 k-floats + 4 pad: keeps 16B alignment, <=4-way read conflicts

__global__ __launch_bounds__(256) void gemm_uv(
    const float* __restrict__ x, const float* __restrict__ U_w,
    const float* __restrict__ U_b, const float* __restrict__ V_w,
    const float* __restrict__ V_b, float* __restrict__ Ux,
    float* __restrict__ Vx) {
  __shared__ float Xs[64 * S36];   // [m][k] 64x32
  __shared__ float Ws[32 * S36];   // [n][k] 32x32
  const int t  = threadIdx.x;
  const int gx = blockIdx.x;   // 0..15: n-tile (32 wide); gx<8 -> U, else V
  const int gy = blockIdx.y;   // 0..31: m-tile (64)
  const int m0 = gy * 64;
  const bool isU = (gx < 8);
  const float* Wsrc = isU ? U_w : V_w;
  const float* bsrc = isU ? U_b : V_b;
  const int n0 = (gx & 7) * 32;
  float* dst = isU ? Ux : Vx;

  const int tn = t & 15;   // n = 2*tn .. +1
  const int tm = t >> 4;   // m = 4*tm .. +3
  float acc[4][2] = {};

  const int lm = t >> 3;   // 0..31
  const int lc = t & 7;    // f4 index along k

  for (int k0 = 0; k0 < 256; k0 += 32) {
    #pragma unroll
    for (int r = 0; r < 2; ++r) {
      const int m = r * 32 + lm;
      f4 v = *(const f4*)(x + (m0 + m) * 256 + k0 + lc * 4);
      *(f4*)(&Xs[m * S36 + lc * 4]) = v;
    }
    {
      f4 v = *(const f4*)(Wsrc + (n0 + lm) * 256 + k0 + lc * 4);
      *(f4*)(&Ws[lm * S36 + lc * 4]) = v;
    }
    __syncthreads();
    #pragma unroll
    for (int kq = 0; kq < 8; ++kq) {
      f4 a0 = *(const f4*)(&Xs[(tm * 4 + 0) * S36 + kq * 4]);
      f4 a1 = *(const f4*)(&Xs[(tm * 4 + 1) * S36 + kq * 4]);
      f4 a2 = *(const f4*)(&Xs[(tm * 4 + 2) * S36 + kq * 4]);
      f4 a3 = *(const f4*)(&Xs[(tm * 4 + 3) * S36 + kq * 4]);
      f4 b0 = *(const f4*)(&Ws[(tn * 2 + 0) * S36 + kq * 4]);
      f4 b1 = *(const f4*)(&Ws[(tn * 2 + 1) * S36 + kq * 4]);
      acc[0][0] += a0.x*b0.x + a0.y*b0.y + a0.z*b0.z + a0.w*b0.w;
      acc[0][1] += a0.x*b1.x + a0.y*b1.y + a0.z*b1.z + a0.w*b1.w;
      acc[1][0] += a1.x*b0.x + a1.y*b0.y + a1.z*b0.z + a1.w*b0.w;
      acc[1][1] += a1.x*b1.x + a1.y*b1.y + a1.z*b1.z + a1.w*b1.w;
      acc[2][0] += a2.x*b0.x + a2.y*b0.y + a2.z*b0.z + a2.w*b0.w;
      acc[2][1] += a2.x*b1.x + a2.y*b1.y + a2.z*b1.z + a2.w*b1.w;
      acc[3][0] += a3.x*b0.x + a3.y*b0.y + a3.z*b0.z + a3.w*b0.w;
      acc[3][1] += a3.x*b1.x + a3.y*b1.y + a3.z*b1.z + a3.w*b1.w;
    }
    __syncthreads();
  }

  const float bb0 = bsrc[n0 + 2 * tn + 0];
  const float bb1 = bsrc[n0 + 2 * tn + 1];
  #pragma unroll
  for (int i = 0; i < 4; ++i) {
    f2 o;
    o.x = acc[i][0] + bb0;
    o.y = acc[i][1] + bb1;
    *(f2*)(dst + (m0 + 4 * tm + i) * 256 + n0 + 2 * tn) = o;
  }
}

// fuse_partial: block = (jc, row); 4 waves; wave w owns j = jc*64+w*16 .. +15.
// lane = f4 index along full h (64 x 16B = one 1KB row per load instruction).
// Writes per-(row,jc) partial num/den (64 f4 each) to `part`.
__global__ __launch_bounds__(256) void fuse_partial(
    const float* __restrict__ eg, const float* __restrict__ Vx,
    float* __restrict__ part) {
  const int t    = threadIdx.x;
  const int lane = t & 63;
  const int w    = t >> 6;      // 0..3
  const int jc   = blockIdx.x;  // 0..3
  const int row  = blockIdx.y;  // 0..2047 (= b*256 + i)
  const int b    = row >> 8;
  const int jb   = jc * 64 + w * 16;

  const f4* ep = (const f4*)eg + ((size_t)row * 256 + jb) * 64 + lane;
  const f4* vp = (const f4*)Vx + ((size_t)b   * 256 + jb) * 64 + lane;

  f4 n0 = {0.f,0.f,0.f,0.f}, n1 = {0.f,0.f,0.f,0.f};
  f4 d0 = {0.f,0.f,0.f,0.f}, d1 = {0.f,0.f,0.f,0.f};

  #pragma unroll
  for (int h = 0; h < 2; ++h) {
    const f4* e8 = ep + h * 8 * 64;
    const f4* v8 = vp + h * 8 * 64;
    f4 e0 = __builtin_nontemporal_load(&e8[0 * 64]);
    f4 e1 = __builtin_nontemporal_load(&e8[1 * 64]);
    f4 e2 = __builtin_nontemporal_load(&e8[2 * 64]);
    f4 e3 = __builtin_nontemporal_load(&e8[3 * 64]);
    f4 e4 = __builtin_nontemporal_load(&e8[4 * 64]);
    f4 e5 = __builtin_nontemporal_load(&e8[5 * 64]);
    f4 e6 = __builtin_nontemporal_load(&e8[6 * 64]);
    f4 e7 = __builtin_nontemporal_load(&e8[7 * 64]);
    f4 v0 = v8[0 * 64];
    f4 v1 = v8[1 * 64];
    f4 v2 = v8[2 * 64];
    f4 v3 = v8[3 * 64];
    f4 v4 = v8[4 * 64];
    f4 v5 = v8[5 * 64];
    f4 v6 = v8[6 * 64];
    f4 v7 = v8[7 * 64];
    n0 += e0 * v0;  d0 += e0;
    n1 += e1 * v1;  d1 += e1;
    n0 += e2 * v2;  d0 += e2;
    n1 += e3 * v3;  d1 += e3;
    n0 += e4 * v4;  d0 += e4;
    n1 += e5 * v5;  d1 += e5;
    n0 += e6 * v6;  d0 += e6;
    n1 += e7 * v7;  d1 += e7;
  }
  const f4 ns = n0 + n1;
  const f4 ds = d0 + d1;

  __shared__ f4 sh[8][64];   // 8 KB
  sh[w][lane]     = ns;
  sh[4 + w][lane] = ds;
  __syncthreads();

  if (t < 64) {
    f4 n = sh[0][t] + sh[1][t] + sh[2][t] + sh[3][t];
    f4 d = sh[4][t] + sh[5][t] + sh[6][t] + sh[7][t];
    f4* p = (f4*)part + (size_t)(row * 4 + jc) * 128;
    p[t]      = n;   // num
    p[64 + t] = d;   // den
  }
}

// combine: out[row,h] = Ux + num/(eps+den), summing the 4 j-chunk partials.
__global__ __launch_bounds__(256) void combine(
    const float* __restrict__ part, float* __restrict__ out) {
  const int idx  = blockIdx.x * 256 + threadIdx.x;  // 0..131071 = row*64+lane
  const int row  = idx >> 6;
  const int lane = idx & 63;
  const f4* p = (const f4*)part + (size_t)row * 4 * 128;
  f4 n = {0.f,0.f,0.f,0.f};
  f4 d = {0.f,0.f,0.f,0.f};
  #pragma unroll
  for (int jc = 0; jc < 4; ++jc) {
    n += p[jc * 128 + lane];
    d += p[jc * 128 + 64 + lane];
  }
  f4 u = ((const f4*)out)[idx];
  f4 eps = {1e-20f, 1e-20f, 1e-20f, 1e-20f};
  ((f4*)out)[idx] = u + n / (eps + d);
}

extern "C" void kernel_launch(void* const* d_in, const int* in_sizes, int n_in,
                              void* d_out, int out_size, void* d_ws, size_t ws_size,
                              hipStream_t stream) {
  const float* x   = (const float*)d_in[0];
  const float* eg  = (const float*)d_in[1];
  const float* U_w = (const float*)d_in[2];
  const float* U_b = (const float*)d_in[3];
  const float* V_w = (const float*)d_in[4];
  const float* V_b = (const float*)d_in[5];
  float* out  = (float*)d_out;
  float* Vx   = (float*)d_ws;                       // 2 MB
  float* part = (float*)d_ws + 2048 * 256;          // 16 MB partials

  gemm_uv<<<dim3(16, 32), 256, 0, stream>>>(x, U_w, U_b, V_w, V_b, out, Vx);
  fuse_partial<<<dim3(4, 2048), 256, 0, stream>>>(eg, Vx, part);
  combine<<<dim3(512), 256, 0, stream>>>(part, out);
}